// Round 10
// baseline (122.179 us; speedup 1.0000x reference)
//
#include <hip/hip_runtime.h>

// PositionalEmbedding: out[node, t*32 + j] = (child_pos(ancestor_t(node)) == j)
// N = 262144, n = 32, k = 16. Output float32 [N, 512] = 512 MiB, write-BW-bound.
// R10: chase/store decoupled. K1: chase -> packed codes (4 MiB, ws).
// K2: per wave, 4 coalesced prologue loads (one vmcnt drain), then 512 KiB of
// pure back-to-back stores (readlane code distribution, zero in-loop memory
// ops, zero chase chain) -- byte-shaped like rocclr fill from the start.

#define NN 32   // one-hot width (n)
#define KK 16   // ancestor depth (k)

typedef float f32x4 __attribute__((ext_vector_type(4)));

// ---- Kernel 1: 16-step chase -> 16 packed code bytes per node ----
__global__ __launch_bounds__(256) void pe_codes(
    const int* __restrict__ parents,
    const int* __restrict__ child_pos,
    uint4* __restrict__ codes_out, int N)
{
    const int node = blockIdx.x * blockDim.x + threadIdx.x;
    if (node >= N) return;
    unsigned int packed[KK / 4];
    int cur = node;
    #pragma unroll
    for (int w = 0; w < KK / 4; ++w) {
        unsigned int u = 0;
        #pragma unroll
        for (int b = 0; b < 4; ++b) {
            const int cp = child_pos[cur];               // independent
            const unsigned int byte = (cp < NN) ? (unsigned int)cp : 0xFFu;
            u |= byte << (8 * b);
            cur = parents[cur];                          // dependent chain
        }
        packed[w] = u;
    }
    codes_out[node] = make_uint4(packed[0], packed[1], packed[2], packed[3]);
}

// ---- Kernel 2: prologue-loaded, wait-free store sweep ----
// Wave wid owns rows [wid*256, wid*256+256) as 4 chunks of 64.
// Prologue: lane l loads codes of row (wid*256 + q*64 + l), q=0..3.
// Sweep: chunk q, iter j -> row wid*256+q*64+j; codes via readlane(cq, j).
__global__ __launch_bounds__(256) void pe_expand_rl(
    const uint4* __restrict__ codes,
    f32x4* __restrict__ out4, int N)
{
    const int lane  = (int)(threadIdx.x & 63);
    const int wid   = (int)((blockIdx.x * blockDim.x + threadIdx.x) >> 6);
    const int wbase = wid * 256;

    // prologue: 4 independent coalesced dwordx4 loads, single drain
    uint4 cq[4];
    #pragma unroll
    for (int q = 0; q < 4; ++q) {
        int row = wbase + q * 64 + lane;
        cq[q] = codes[(row < N) ? row : 0];
    }

    const bool hi32 = (lane >= 32);
    const int  sh   = ((lane >> 3) & 3) * 8;   // byte-in-dword shift
    const int  q4   = (lane & 7) * 4;          // one-hot quad base

    #pragma unroll
    for (int q = 0; q < 4; ++q) {
        if (wbase + q * 64 >= N) break;        // wave-uniform guard
        f32x4* wout = out4 + (size_t)(wbase + q * 64) * 128 + lane;
        #pragma unroll 4
        for (int j = 0; j < 64; ++j) {
            const unsigned s0 = (unsigned)__builtin_amdgcn_readlane((int)cq[q].x, j);
            const unsigned s1 = (unsigned)__builtin_amdgcn_readlane((int)cq[q].y, j);
            const unsigned s2 = (unsigned)__builtin_amdgcn_readlane((int)cq[q].z, j);
            const unsigned s3 = (unsigned)__builtin_amdgcn_readlane((int)cq[q].w, j);

            const int code0 = (int)(((hi32 ? s1 : s0) >> sh) & 0xFFu);
            const int code1 = (int)(((hi32 ? s3 : s2) >> sh) & 0xFFu);

            f32x4 v0, v1;
            v0.x = (code0 == q4    ) ? 1.0f : 0.0f;
            v0.y = (code0 == q4 + 1) ? 1.0f : 0.0f;
            v0.z = (code0 == q4 + 2) ? 1.0f : 0.0f;
            v0.w = (code0 == q4 + 3) ? 1.0f : 0.0f;
            v1.x = (code1 == q4    ) ? 1.0f : 0.0f;
            v1.y = (code1 == q4 + 1) ? 1.0f : 0.0f;
            v1.z = (code1 == q4 + 2) ? 1.0f : 0.0f;
            v1.w = (code1 == q4 + 3) ? 1.0f : 0.0f;

            wout[(size_t)j * 128]      = v0;   // 1 KiB/wave, coalesced
            wout[(size_t)j * 128 + 64] = v1;
        }
    }
}

// ---- Fallback: R6 fused (111.3 us) if ws too small ----
__global__ __launch_bounds__(256) void pe_fused_rl(
    const int* __restrict__ parents,
    const int* __restrict__ child_pos,
    f32x4* __restrict__ out4, int N)
{
    const int lane  = (int)(threadIdx.x & 63);
    const int wid   = (int)((blockIdx.x * blockDim.x + threadIdx.x) >> 6);
    const int wbase = wid * 64;
    const int node  = wbase + lane;

    unsigned int c[4];
    {
        int cur = (node < N) ? node : N;
        #pragma unroll
        for (int w = 0; w < 4; ++w) {
            unsigned int u = 0;
            #pragma unroll
            for (int b = 0; b < 4; ++b) {
                const int cp = child_pos[cur];
                const unsigned int byte = (cp < NN) ? (unsigned int)cp : 0xFFu;
                u |= byte << (8 * b);
                cur = parents[cur];
            }
            c[w] = u;
        }
    }

    const bool hi32 = (lane >= 32);
    const int  sh   = ((lane >> 3) & 3) * 8;
    const int  q4   = (lane & 7) * 4;

    f32x4* wout = out4 + (size_t)wbase * 128 + lane;

    #pragma unroll 4
    for (int r = 0; r < 64; ++r) {
        const unsigned s0 = (unsigned)__builtin_amdgcn_readlane((int)c[0], r);
        const unsigned s1 = (unsigned)__builtin_amdgcn_readlane((int)c[1], r);
        const unsigned s2 = (unsigned)__builtin_amdgcn_readlane((int)c[2], r);
        const unsigned s3 = (unsigned)__builtin_amdgcn_readlane((int)c[3], r);

        const int code0 = (int)(((hi32 ? s1 : s0) >> sh) & 0xFFu);
        const int code1 = (int)(((hi32 ? s3 : s2) >> sh) & 0xFFu);

        f32x4 v0, v1;
        v0.x = (code0 == q4    ) ? 1.0f : 0.0f;
        v0.y = (code0 == q4 + 1) ? 1.0f : 0.0f;
        v0.z = (code0 == q4 + 2) ? 1.0f : 0.0f;
        v0.w = (code0 == q4 + 3) ? 1.0f : 0.0f;
        v1.x = (code1 == q4    ) ? 1.0f : 0.0f;
        v1.y = (code1 == q4 + 1) ? 1.0f : 0.0f;
        v1.z = (code1 == q4 + 2) ? 1.0f : 0.0f;
        v1.w = (code1 == q4 + 3) ? 1.0f : 0.0f;

        wout[(size_t)r * 128]      = v0;
        wout[(size_t)r * 128 + 64] = v1;
    }
}

extern "C" void kernel_launch(void* const* d_in, const int* in_sizes, int n_in,
                              void* d_out, int out_size, void* d_ws, size_t ws_size,
                              hipStream_t stream) {
    const int* parents   = (const int*)d_in[0];
    const int* child_pos = (const int*)d_in[1];
    f32x4* out4 = (f32x4*)d_out;

    const int N = in_sizes[0] - 1;                 // 262144

    if (ws_size >= (size_t)N * KK) {
        pe_codes<<<(N + 255) / 256, 256, 0, stream>>>(
            parents, child_pos, (uint4*)d_ws, N);

        const int n_waves = (N + 255) / 256;       // 1024 waves, 256 rows each
        const int grid    = (n_waves + 3) / 4;     // 256 blocks
        pe_expand_rl<<<grid, 256, 0, stream>>>((const uint4*)d_ws, out4, N);
    } else {
        const int n_waves = (N + 63) / 64;
        const int grid    = (n_waves + 3) / 4;
        pe_fused_rl<<<grid, 256, 0, stream>>>(parents, child_pos, out4, N);
    }
}

// Round 11
// 112.491 us; speedup vs baseline: 1.0861x; 1.0861x over previous
//
#include <hip/hip_runtime.h>

// PositionalEmbedding: out[node, t*32 + j] = (child_pos(ancestor_t(node)) == j)
// N = 262144, n = 32, k = 16. Output float32 [N, 512] = 512 MiB, write-BW-bound.
// R11: R9 geometry (1024 waves x 256 rows in 4 chunks of 64) with SOFTWARE-
// PIPELINED chase: chunk q+1's 16-round dependent chain is interleaved into
// chunk q's 64-iteration store sweep (1 round per 4 store iters), so the
// pointer-chase latency hides under the store stream instead of stalling the
// whole GPU for ~8-10 us up front. Only chunk 0's chase remains exposed.

#define NN 32   // one-hot width (n)
#define KK 16   // ancestor depth (k)

typedef float f32x4 __attribute__((ext_vector_type(4)));

__global__ __launch_bounds__(256) void pe_pipe(
    const int* __restrict__ parents,
    const int* __restrict__ child_pos,
    f32x4* __restrict__ out4, int N)
{
    const int lane  = (int)(threadIdx.x & 63);
    const int wid   = (int)((blockIdx.x * blockDim.x + threadIdx.x) >> 6);
    const int wbase = wid * 256;               // this wave's 256 rows
    if (wbase >= N) return;

    // ---- Prologue: chase chunk 0 only (16-round dependent chain) ----
    unsigned int c[4];
    {
        int cur = wbase + lane;
        if (cur >= N) cur = N;
        #pragma unroll
        for (int w = 0; w < 4; ++w) {
            unsigned int u = 0;
            #pragma unroll
            for (int b = 0; b < 4; ++b) {
                const int cp = child_pos[cur];
                const unsigned int byte = (cp < NN) ? (unsigned int)cp : 0xFFu;
                u |= byte << (8 * b);
                cur = parents[cur];
            }
            c[w] = u;
        }
    }

    const bool hi32 = (lane >= 32);
    const int  sh   = ((lane >> 3) & 3) * 8;   // byte-in-dword shift
    const int  q4   = (lane & 7) * 4;          // one-hot quad base

    // pipeline state for the next chunk's chase
    unsigned long long ulo = 0, uhi = 0;       // accumulating 16 code bytes
    int cp_p = 0, par_p = 0;                   // in-flight round's loads

    #pragma unroll
    for (int q = 0; q < 4; ++q) {
        if (wbase + q * 64 >= N) break;        // wave-uniform guard
        f32x4* wout = out4 + (size_t)(wbase + q * 64) * 128 + lane;

        if (q < 3) {                           // issue round 0 of chunk q+1
            int cur0 = wbase + (q + 1) * 64 + lane;
            if (cur0 >= N) cur0 = N;
            cp_p  = child_pos[cur0];
            par_p = parents[cur0];
            ulo = 0; uhi = 0;
        }

        #pragma unroll 1
        for (int jj = 0; jj < 16; ++jj) {
            if (q < 3 && jj > 0) {
                // consume round jj-1 -> byte jj-1; issue round jj
                const unsigned int byte = (cp_p < NN) ? (unsigned int)cp_p : 0xFFu;
                const int r = jj - 1;
                if (r < 8) ulo |= (unsigned long long)byte << (8 * r);
                else       uhi |= (unsigned long long)byte << (8 * (r - 8));
                const int cur = par_p;
                cp_p  = child_pos[cur];
                par_p = parents[cur];
            }
            #pragma unroll
            for (int m = 0; m < 4; ++m) {
                const int j = jj * 4 + m;      // row within chunk
                const unsigned s0 = (unsigned)__builtin_amdgcn_readlane((int)c[0], j);
                const unsigned s1 = (unsigned)__builtin_amdgcn_readlane((int)c[1], j);
                const unsigned s2 = (unsigned)__builtin_amdgcn_readlane((int)c[2], j);
                const unsigned s3 = (unsigned)__builtin_amdgcn_readlane((int)c[3], j);

                const int code0 = (int)(((hi32 ? s1 : s0) >> sh) & 0xFFu);
                const int code1 = (int)(((hi32 ? s3 : s2) >> sh) & 0xFFu);

                f32x4 v0, v1;
                v0.x = (code0 == q4    ) ? 1.0f : 0.0f;
                v0.y = (code0 == q4 + 1) ? 1.0f : 0.0f;
                v0.z = (code0 == q4 + 2) ? 1.0f : 0.0f;
                v0.w = (code0 == q4 + 3) ? 1.0f : 0.0f;
                v1.x = (code1 == q4    ) ? 1.0f : 0.0f;
                v1.y = (code1 == q4 + 1) ? 1.0f : 0.0f;
                v1.z = (code1 == q4 + 2) ? 1.0f : 0.0f;
                v1.w = (code1 == q4 + 3) ? 1.0f : 0.0f;

                wout[(size_t)j * 128]      = v0;   // 1 KiB/wave, coalesced
                wout[(size_t)j * 128 + 64] = v1;
            }
        }

        if (q < 3) {
            // final consume: round 15 -> byte 15; repack into c[] for chunk q+1
            const unsigned int byte = (cp_p < NN) ? (unsigned int)cp_p : 0xFFu;
            uhi |= (unsigned long long)byte << (8 * 7);
            c[0] = (unsigned int)ulo;
            c[1] = (unsigned int)(ulo >> 32);
            c[2] = (unsigned int)uhi;
            c[3] = (unsigned int)(uhi >> 32);
        }
    }
}

extern "C" void kernel_launch(void* const* d_in, const int* in_sizes, int n_in,
                              void* d_out, int out_size, void* d_ws, size_t ws_size,
                              hipStream_t stream) {
    const int* parents   = (const int*)d_in[0];
    const int* child_pos = (const int*)d_in[1];
    f32x4* out4 = (f32x4*)d_out;

    const int N = in_sizes[0] - 1;                 // 262144
    const int n_waves = (N + 255) / 256;           // 1024 waves, 256 rows each
    const int grid    = (n_waves + 3) / 4;         // 256 blocks of 256 threads

    pe_pipe<<<grid, 256, 0, stream>>>(parents, child_pos, out4, N);
}